// Round 5
// baseline (361.231 us; speedup 1.0000x reference)
//
#include <hip/hip_runtime.h>

// Rotated RoIAlign, feature (B,C,H,W)=(4,256,256,256) f32, boxes (B,M,7),
// out (B*M, 7, 7, C) f32, P=7, S=2.
//
// Round-5: block = (box, 16-channel group), grid (16, 400).
//  - Cooperative sample table (196 threads): ONE LDS base offset per sample
//    + 4 valid/edge-masked weights. All 4 bilinear taps are read from that
//    single base at immediate offsets {0, +1, +17, +18} -> the compiler
//    emits 2x ds_read2_b32 per sample (was 4x ds_read_b32 + 4 addr calcs).
//    Edge-clamped taps (x0>=W-1 or y0>=H-1) get weight 0; their padded read
//    lands on a STAGED pixel (region is 17 wide, rows staged to max(ly0)+2
//    via LDS atomicMax -> every read row/col staged by construction, the
//    mechanism that fixed round-3's unstaged-read bug).
//  - Region layout [c][pix], pix = y*17 + x, per-channel stride 289 floats
//    (odd -> compute-phase banks (c*289+o)%32 distinct across c-lanes).
//  - CG=16: LDS 16*289*4 + tables ~= 22.4 KB -> ~7 blocks/CU, 6400 blocks.

#define RP 7
#define RS 2
#define RGW 17                      // region cols (16 + 1 pad for x1 reads)
#define RGH 17                      // region rows max (16 + 1 pad)
#define CG 16
#define CPIX (RGW * RGH)            // 289 (odd stride -> bank-safe)
#define NSAMP (RP * RP * RS * RS)   // 196

__global__ __launch_bounds__(256) void roialign_kernel(
    const float* __restrict__ feature,
    const float* __restrict__ boxes,
    float* __restrict__ out,
    int C, int H, int W, int M)
{
    __shared__ float  sm[CG * CPIX];    // 18.5 KB
    __shared__ float4 swt[NSAMP];       // 3.1 KB
    __shared__ int    soff[NSAMP];      // 0.8 KB
    __shared__ int    srowmax;

    const int g = blockIdx.x;   // channel group 0..15
    const int n = blockIdx.y;   // box 0..399
    const int t = threadIdx.x;
    const int b = n / M;

    const float gw = 281.6f / (float)W;   // 1.1
    const float gh = 80.0f  / (float)H;   // 0.3125

    const float* bx = boxes + n * 7;
    const float cx = (bx[0] + 140.8f) / gw - 0.5f;
    const float cy = (bx[1] + 40.0f)  / gh - 0.5f;
    const float rw = bx[5] / gw;          // ENLARGE = 1.0
    const float rh = bx[4] / gh;
    const float theta = -bx[6];
    const float ct = cosf(theta), st = sinf(theta);
    const float bw = rw / (float)RP, bh = rh / (float)RP;

    // Region origin from rotated-box extent (positions the window only; the
    // staged ROW COUNT comes from the table below).
    const float ex = 0.5f * (fabsf(rw * ct) + fabsf(rh * st));
    const float ey = 0.5f * (fabsf(rw * st) + fabsf(rh * ct));
    const int rx0 = min(max(0, (int)floorf(cx - ex)), W - 1);
    const int ry0 = min(max(0, (int)floorf(cy - ey)), H - 1);

    if (t == 0) srowmax = 0;
    __syncthreads();

    // ---- sample table: thread s<196 handles one (bin, subsample)
    const float Hf = (float)H, Wf = (float)W;
    if (t < NSAMP) {
        const int bin = t >> 2;
        const int v = (t >> 1) & 1;
        const int u = t & 1;
        const int j = bin / RP;
        const int i = bin - j * RP;
        const float yy = -rh * 0.5f + bh * ((float)j + ((float)v + 0.5f) / (float)RS);
        const float xx = -rw * 0.5f + bw * ((float)i + ((float)u + 0.5f) / (float)RS);
        float y = yy * ct - xx * st + cy;
        float x = yy * st + xx * ct + cx;
        const bool valid = (y > -1.0f) & (y < Hf) & (x > -1.0f) & (x < Wf);
        y = fmaxf(y, 0.0f);
        x = fmaxf(x, 0.0f);
        const int y0 = min((int)floorf(y), H - 1);
        const int x0 = min((int)floorf(x), W - 1);
        // Reference semantics: if y0>=H-1 then ly=0 (so the y1 tap has zero
        // weight); same for x. The padded tap we read instead of the clamped
        // one is staged and weight-0 -> contributes an exact 0.
        const float ly = (y0 >= H - 1) ? 0.0f : (y - (float)y0);
        const float lx = (x0 >= W - 1) ? 0.0f : (x - (float)x0);
        const float hy = 1.0f - ly;
        const float hx = 1.0f - lx;
        const int ly0 = min(max(y0 - ry0, 0), RGH - 2);  // <=15
        const int lx0 = min(max(x0 - rx0, 0), RGW - 2);  // <=15
        soff[t] = valid ? (ly0 * RGW + lx0) : 0;
        float4 w;
        w.x = valid ? (hy * hx) : 0.0f;
        w.y = valid ? (hy * lx) : 0.0f;
        w.z = valid ? (ly * hx) : 0.0f;
        w.w = valid ? (ly * lx) : 0.0f;
        swt[t] = w;
        atomicMax(&srowmax, valid ? ly0 : 0);  // reads touch rows <= ly0+1
    }
    __syncthreads();

    // ---- stage rows [0, srowmax+2): every read row is staged by construction
    const int npix = (srowmax + 2) * RGW;      // <= 289
    // thread t covers region pixels t and t+256 (y/x maps are ny-independent)
    const int y0p = t / RGW,        x0p = t - y0p * RGW;
    const int y1p = (t + 256) / RGW, x1p = (t + 256) - y1p * RGW;
    const size_t planeHW = (size_t)H * W;
    const float* fplane = feature + (size_t)(b * C + g * CG) * planeHW;
    const int g0 = min(ry0 + y0p, H - 1) * W + min(rx0 + x0p, W - 1);
    const int g1 = min(ry0 + y1p, H - 1) * W + min(rx0 + x1p, W - 1);
    const bool p0 = (t < npix), p1 = (t + 256 < npix);
    #pragma unroll
    for (int cs = 0; cs < CG; ++cs) {
        const float* pl = fplane + (size_t)cs * planeHW;
        if (p0) sm[cs * CPIX + t]       = pl[g0];
        if (p1) sm[cs * CPIX + t + 256] = pl[g1];
    }
    __syncthreads();

    // ---- compute: lane c = t&15 (channel), slice = t>>4 strides over bins
    const int c = t & (CG - 1);
    const int slice = t >> 4;            // 0..15
    const float* __restrict__ smc = sm + c * CPIX;
    float* __restrict__ outn = out + ((size_t)n * (RP * RP)) * C + g * CG + c;

    for (int bidx = slice; bidx < RP * RP; bidx += 16) {
        float acc = 0.0f;
        #pragma unroll
        for (int sub = 0; sub < RS * RS; ++sub) {
            const int    o = soff[bidx * 4 + sub];
            const float4 w = swt[bidx * 4 + sub];
            // 4 taps from one base: {0,+1} and {+17,+18} -> 2x ds_read2_b32
            acc += w.x * smc[o]       + w.y * smc[o + 1]
                 + w.z * smc[o + RGW] + w.w * smc[o + RGW + 1];
        }
        outn[(size_t)bidx * C] = acc * (1.0f / (RS * RS));
    }
}

extern "C" void kernel_launch(void* const* d_in, const int* in_sizes, int n_in,
                              void* d_out, int out_size, void* d_ws, size_t ws_size,
                              hipStream_t stream) {
    const float* feature = (const float*)d_in[0];
    const float* boxes   = (const float*)d_in[1];
    float* out = (float*)d_out;

    const int C = 256, H = 256, W = 256;
    const int N = in_sizes[1] / 7;            // B*M = 400
    const int B = in_sizes[0] / (C * H * W);  // 4
    const int M = N / B;                      // 100

    dim3 grid(C / CG, N);   // (16, 400)
    dim3 block(256);
    roialign_kernel<<<grid, block, 0, stream>>>(feature, boxes, out, C, H, W, M);
}